// Round 9
// baseline (769.606 us; speedup 1.0000x reference)
//
#include <hip/hip_runtime.h>

#define TB 2
#define TL 2048
#define TE 1024
#define TH 16
#define TA 64

typedef __bf16 bf16;
typedef __bf16 bf16x4 __attribute__((ext_vector_type(4)));
typedef __bf16 bf16x8 __attribute__((ext_vector_type(8)));
typedef float f32x4 __attribute__((ext_vector_type(4)));

#define AS1 __attribute__((address_space(1)))
#define AS3 __attribute__((address_space(3)))

__device__ __forceinline__ void gload_lds16(const void* g, void* l) {
    __builtin_amdgcn_global_load_lds((const AS1 void*)g, (AS3 void*)l, 16, 0, 0);
}

// ---------------- f32 -> bf16 convert (vectorized) ----------------
__global__ __launch_bounds__(256)
void cvt_bf16(const float* __restrict__ in, bf16* __restrict__ out, int n4) {
    int i = blockIdx.x * 256 + threadIdx.x;
    if (i < n4) {
        float4 v = reinterpret_cast<const float4*>(in)[i];
        bf16x4 o = { (bf16)v.x, (bf16)v.y, (bf16)v.z, (bf16)v.w };
        reinterpret_cast<bf16x4*>(out)[i] = o;
    }
}

// ---------------- bf16 GEMM: C[M,N] = A[M,1024] @ W[N,1024]^T ----------------
// 2-phase pipelined (T3 minimum): stage K-tile k+1 into buf^1 BEFORE computing
// tile k, so the __syncthreads vmcnt(0) drain overlaps stage latency with
// ds_read+MFMA instead of exposing it (R7 was 1 block/CU -> no overlap).
template<int OUT_MODE>
__global__ __launch_bounds__(256)
void gemm_bt(const bf16* __restrict__ A, const bf16* __restrict__ W, void* Cp) {
    __shared__ __align__(16) bf16 As[2][128 * 32];
    __shared__ __align__(16) bf16 Bs[2][128 * 32];
    const int t = threadIdx.x, l = t & 63, w = t >> 6;
    const int m0 = blockIdx.y * 128, n0 = blockIdx.x * 128;
    const int wm = w >> 1, wn = w & 1;

    f32x4 acc[4][4] = {};

    const int rowS = t >> 2;
    const int kbyt = (t & 3) * 16;
    const char* Ag0 = (const char*)(A + (size_t)(m0 + rowS) * 1024) + kbyt;
    const char* Bg0 = (const char*)(W + (size_t)(n0 + rowS) * 1024) + kbyt;
    const int ROWB = 64 * 1024 * 2;           // +64 rows in bytes

    auto stage = [&](int buf, int k0) {
        const int kB = k0 * 2;
        char* AsB = (char*)As[buf] + w * 1024;
        char* BsB = (char*)Bs[buf] + w * 1024;
        gload_lds16(Ag0 + kB, AsB);
        gload_lds16(Ag0 + kB + ROWB, AsB + 4096);
        gload_lds16(Bg0 + kB, BsB);
        gload_lds16(Bg0 + kB + ROWB, BsB + 4096);
    };

    stage(0, 0);
    __syncthreads();                           // drain prologue stage
    int cur = 0;
    #pragma unroll 1
    for (int step = 0; step < 32; ++step) {
        if (step + 1 < 32) stage(cur ^ 1, (step + 1) * 32);   // prefetch next
        bf16x8 af[4], bfr[4];
        #pragma unroll
        for (int mf = 0; mf < 4; ++mf)
            af[mf] = *reinterpret_cast<const bf16x8*>(
                (const char*)As[cur] + (wm * 64 + mf * 16 + (l & 15)) * 64 + (l >> 4) * 16);
        #pragma unroll
        for (int nf = 0; nf < 4; ++nf)
            bfr[nf] = *reinterpret_cast<const bf16x8*>(
                (const char*)Bs[cur] + (wn * 64 + nf * 16 + (l & 15)) * 64 + (l >> 4) * 16);
        #pragma unroll
        for (int mf = 0; mf < 4; ++mf)
            #pragma unroll
            for (int nf = 0; nf < 4; ++nf)
                acc[mf][nf] = __builtin_amdgcn_mfma_f32_16x16x32_bf16(
                    af[mf], bfr[nf], acc[mf][nf], 0, 0, 0);
        __syncthreads();       // waits next-tile stage; protects buf reuse
        cur ^= 1;
    }

    // Epilogue. C/D frag: col = l&15, row = (l>>4)*4 + r.
    if (OUT_MODE == 0) {
        float* C = (float*)Cp;
        #pragma unroll
        for (int mf = 0; mf < 4; ++mf) {
            const int m = m0 + wm * 64 + mf * 16 + (l >> 4) * 4;
            #pragma unroll
            for (int nf = 0; nf < 4; ++nf) {
                const int n = n0 + wn * 64 + nf * 16 + (l & 15);
                #pragma unroll
                for (int r = 0; r < 4; ++r)
                    C[(size_t)(m + r) * 1024 + n] = acc[mf][nf][r];
            }
        }
    } else {
        bf16* vT = (bf16*)Cp;   // [32 bh][64 a][2048 l]
        #pragma unroll
        for (int mf = 0; mf < 4; ++mf) {
            const int m = m0 + wm * 64 + mf * 16 + (l >> 4) * 4;
            const int b = m >> 11, lp = m & 2047;
            #pragma unroll
            for (int nf = 0; nf < 4; ++nf) {
                const int n = n0 + wn * 64 + nf * 16 + (l & 15);
                const int h = n >> 6, a = n & 63;
                bf16x4 o = { (bf16)acc[mf][nf][0], (bf16)acc[mf][nf][1],
                             (bf16)acc[mf][nf][2], (bf16)acc[mf][nf][3] };
                *reinterpret_cast<bf16x4*>(
                    &vT[((size_t)(b * TH + h) * TA + a) * TL + lp]) = o;
            }
        }
    }
}

// ---------------- fused causal softmax + P@V (MFMA, barrier-free) ----------------
// Each wave fully independent: 16 q-rows, no LDS, no __syncthreads. B-frags
// read directly from global vT (L2/L3-resident: 256KB per bh; all q-tiles of a
// bh map to one XCD since linear block id stride 32 = 0 mod 8). Latency hidden
// by TLP (4096 waves all resident). P math identical to the R7-passing version.
__global__ __launch_bounds__(256)
void attn_mfma(const float* __restrict__ Wt,   // [B,H,L,L] f32
               const bf16* __restrict__ vT,    // [32][64][2048] bf16
               bf16* __restrict__ Vals) {      // [B,L,E] bf16
    const int t = threadIdx.x, l = t & 63, w = t >> 6;
    const int bh = blockIdx.x;
    const int q0 = (31 - (int)blockIdx.y) * 64;      // heavy tiles first
    const int qg = q0 + w * 16 + (l & 15);
    const float* wrow = Wt + (size_t)bh * TL * TL + (size_t)qg * TL;
    const bf16* vTb = vT + (size_t)bh * TA * TL;
    const int kq = (l >> 4) * 8;                     // k sub-offset (elems)

    f32x4 acc[4] = {};
    float rs = 0.f;
    const int nk = (q0 >> 6) + 1;

    #pragma unroll 1
    for (int kt = 0; kt < nk; ++kt) {
        const int k0 = kt << 6;
        // B-frags: lane l -> vT row a = nf*16 + (l&15), 8 contiguous k's (16B)
        bf16x8 bfr[4][2];
        #pragma unroll
        for (int nf = 0; nf < 4; ++nf)
            #pragma unroll
            for (int kk = 0; kk < 2; ++kk)
                bfr[nf][kk] = *reinterpret_cast<const bf16x8*>(
                    vTb + (size_t)(nf * 16 + (l & 15)) * TL + k0 + kk * 32 + kq);
        // A-frags: P = exp(w) with causal mask, register-direct; rowsum
        bf16x8 pa[2];
        #pragma unroll
        for (int kk = 0; kk < 2; ++kk) {
            const float* wp = wrow + k0 + kk * 32 + kq;
            const float4 x0 = *reinterpret_cast<const float4*>(wp);
            const float4 x1 = *reinterpret_cast<const float4*>(wp + 4);
            const float xs[8] = {x0.x, x0.y, x0.z, x0.w, x1.x, x1.y, x1.z, x1.w};
            #pragma unroll
            for (int j = 0; j < 8; ++j) {
                const int kgl = k0 + kk * 32 + kq + j;
                const float p = (kgl <= qg) ? __expf(xs[j]) : 0.f;
                rs += p;
                pa[kk][j] = (bf16)p;
            }
        }
        #pragma unroll
        for (int nf = 0; nf < 4; ++nf) {
            acc[nf] = __builtin_amdgcn_mfma_f32_16x16x32_bf16(pa[0], bfr[nf][0], acc[nf], 0, 0, 0);
            acc[nf] = __builtin_amdgcn_mfma_f32_16x16x32_bf16(pa[1], bfr[nf][1], acc[nf], 0, 0, 0);
        }
    }

    // row sums: reduce over the 4 lanes sharing l&15 (k-quarters)
    rs += __shfl_xor(rs, 16);
    rs += __shfl_xor(rs, 32);
    float inv[4];
    #pragma unroll
    for (int r = 0; r < 4; ++r)
        inv[r] = 1.f / __shfl(rs, ((l >> 4) << 2) + r);

    const int b = bh >> 4, h = bh & 15;
    #pragma unroll
    for (int nf = 0; nf < 4; ++nf) {
        const int e = h * 64 + nf * 16 + (l & 15);
        #pragma unroll
        for (int r = 0; r < 4; ++r) {
            const int qq = q0 + w * 16 + (l >> 4) * 4 + r;
            Vals[(size_t)(b * TL + qq) * TE + e] = (bf16)(acc[nf][r] * inv[r]);
        }
    }
}

extern "C" void kernel_launch(void* const* d_in, const int* in_sizes, int n_in,
                              void* d_out, int out_size, void* d_ws, size_t ws_size,
                              hipStream_t stream) {
    const float* emb   = (const float*)d_in[0];
    const float* wts   = (const float*)d_in[1];
    const float* V_w   = (const float*)d_in[3];
    const float* out_w = (const float*)d_in[4];
    float* out = (float*)d_out;

    bf16* embB = (bf16*)d_ws;                         // 4M elems
    bf16* VwB  = embB + (size_t)4096 * 1024;          // 1M
    bf16* OwB  = VwB + (size_t)1024 * 1024;           // 1M
    bf16* vT   = OwB + (size_t)1024 * 1024;           // 4M  [32][64][2048]
    bf16* vals = vT  + (size_t)4096 * 1024;           // 4M  [B,L,E]

    cvt_bf16<<<4096, 256, 0, stream>>>(emb, embB, 1024 * 1024);
    cvt_bf16<<<1024, 256, 0, stream>>>(V_w, VwB, 256 * 1024);
    cvt_bf16<<<1024, 256, 0, stream>>>(out_w, OwB, 256 * 1024);

    dim3 gg(1024 / 128, 4096 / 128);                  // 8 x 32
    gemm_bt<1><<<gg, 256, 0, stream>>>(embB, VwB, (void*)vT);

    dim3 ga(32, 32);                                  // (bh, q-tile)
    attn_mfma<<<ga, 256, 0, stream>>>(wts, vT, vals);

    gemm_bt<0><<<gg, 256, 0, stream>>>(vals, OwB, (void*)out);
}

// Round 10
// 755.590 us; speedup vs baseline: 1.0185x; 1.0185x over previous
//
#include <hip/hip_runtime.h>

#define TB 2
#define TL 2048
#define TE 1024
#define TH 16
#define TA 64

typedef __bf16 bf16;
typedef __bf16 bf16x4 __attribute__((ext_vector_type(4)));
typedef __bf16 bf16x8 __attribute__((ext_vector_type(8)));
typedef float f32x4 __attribute__((ext_vector_type(4)));

#define AS1 __attribute__((address_space(1)))
#define AS3 __attribute__((address_space(3)))

__device__ __forceinline__ void gload_lds16(const void* g, void* l) {
    __builtin_amdgcn_global_load_lds((const AS1 void*)g, (AS3 void*)l, 16, 0, 0);
}

// ---------------- fused f32 -> bf16 convert, all three tensors ----------------
// 6144 blocks x 256 thr x 1 float4 = 1.572M float4 = emb(1M) | V_w(256K) | out_w(256K)
__global__ __launch_bounds__(256)
void cvt_all(const float* __restrict__ emb, const float* __restrict__ vw,
             const float* __restrict__ ow, bf16* __restrict__ embB,
             bf16* __restrict__ vwB, bf16* __restrict__ owB) {
    const int i = blockIdx.x * 256 + threadIdx.x;
    const float* src; bf16* dst; int off;
    if (i < 1048576)      { src = emb; dst = embB; off = i; }
    else if (i < 1310720) { src = vw;  dst = vwB;  off = i - 1048576; }
    else                  { src = ow;  dst = owB;  off = i - 1310720; }
    const float4 v = reinterpret_cast<const float4*>(src)[off];
    bf16x4 o = { (bf16)v.x, (bf16)v.y, (bf16)v.z, (bf16)v.w };
    reinterpret_cast<bf16x4*>(dst)[off] = o;
}

// ---------------- bf16 GEMM: C[M,N] = A[M,1024] @ W[N,1024]^T ----------------
// 64x64 tile (grid 1024 = 4 blocks/CU, 16 waves/CU -- R9's 128^2 grid of 256
// gave 1 wave/SIMD, no latency hiding). 2-phase dbuf: stage k+1 before
// computing k. 4 waves (2x2), each 32x32 out = 2x2 16x16 frags. BK=32.
// OUT_MODE 0: f32 C[M][1024].  OUT_MODE 1: bf16 v^T [b*16+h][a][2048].
template<int OUT_MODE>
__global__ __launch_bounds__(256)
void gemm_bt(const bf16* __restrict__ A, const bf16* __restrict__ W, void* Cp) {
    __shared__ __align__(16) bf16 As[2][64 * 32];
    __shared__ __align__(16) bf16 Bs[2][64 * 32];
    const int t = threadIdx.x, l = t & 63, w = t >> 6;
    const int m0 = blockIdx.y * 64, n0 = blockIdx.x * 64;
    const int wm = w >> 1, wn = w & 1;

    f32x4 acc[2][2] = {};

    // chunk o = t*16 B of the 4KB tile; row = o>>6, kbyte = o&63
    const int rowS = t >> 2;
    const int kbyt = (t & 3) * 16;
    const char* Ag0 = (const char*)(A + (size_t)(m0 + rowS) * 1024) + kbyt;
    const char* Bg0 = (const char*)(W + (size_t)(n0 + rowS) * 1024) + kbyt;

    auto stage = [&](int buf, int k0) {
        const int kB = k0 * 2;
        gload_lds16(Ag0 + kB, (char*)As[buf] + w * 1024);
        gload_lds16(Bg0 + kB, (char*)Bs[buf] + w * 1024);
    };

    stage(0, 0);
    __syncthreads();
    int cur = 0;
    #pragma unroll 1
    for (int step = 0; step < 32; ++step) {
        if (step + 1 < 32) stage(cur ^ 1, (step + 1) * 32);
        bf16x8 af[2], bfr[2];
        #pragma unroll
        for (int mf = 0; mf < 2; ++mf)
            af[mf] = *reinterpret_cast<const bf16x8*>(
                (const char*)As[cur] + (wm * 32 + mf * 16 + (l & 15)) * 64 + (l >> 4) * 16);
        #pragma unroll
        for (int nf = 0; nf < 2; ++nf)
            bfr[nf] = *reinterpret_cast<const bf16x8*>(
                (const char*)Bs[cur] + (wn * 32 + nf * 16 + (l & 15)) * 64 + (l >> 4) * 16);
        #pragma unroll
        for (int mf = 0; mf < 2; ++mf)
            #pragma unroll
            for (int nf = 0; nf < 2; ++nf)
                acc[mf][nf] = __builtin_amdgcn_mfma_f32_16x16x32_bf16(
                    af[mf], bfr[nf], acc[mf][nf], 0, 0, 0);
        __syncthreads();       // waits prefetched stage; protects buf reuse
        cur ^= 1;
    }

    // Epilogue. C/D frag: col = l&15, row = (l>>4)*4 + r.
    if (OUT_MODE == 0) {
        float* C = (float*)Cp;
        #pragma unroll
        for (int mf = 0; mf < 2; ++mf) {
            const int m = m0 + wm * 32 + mf * 16 + (l >> 4) * 4;
            #pragma unroll
            for (int nf = 0; nf < 2; ++nf) {
                const int n = n0 + wn * 32 + nf * 16 + (l & 15);
                #pragma unroll
                for (int r = 0; r < 4; ++r)
                    C[(size_t)(m + r) * 1024 + n] = acc[mf][nf][r];
            }
        }
    } else {
        bf16* vT = (bf16*)Cp;   // [32 bh][64 a][2048 l]
        #pragma unroll
        for (int mf = 0; mf < 2; ++mf) {
            const int m = m0 + wm * 32 + mf * 16 + (l >> 4) * 4;
            const int b = m >> 11, lp = m & 2047;
            #pragma unroll
            for (int nf = 0; nf < 2; ++nf) {
                const int n = n0 + wn * 32 + nf * 16 + (l & 15);
                const int h = n >> 6, a = n & 63;   // n0=bx*64 -> h = bx
                bf16x4 o = { (bf16)acc[mf][nf][0], (bf16)acc[mf][nf][1],
                             (bf16)acc[mf][nf][2], (bf16)acc[mf][nf][3] };
                *reinterpret_cast<bf16x4*>(
                    &vT[((size_t)(b * TH + h) * TA + a) * TL + lp]) = o;
            }
        }
    }
}

// ---------------- fused causal softmax + P@V (MFMA, barrier-free) ----------------
// UNCHANGED from R9 (control). Wave-independent, no LDS/barriers; B-frags
// direct from L2-resident vT; P register-direct from f32 weights.
__global__ __launch_bounds__(256)
void attn_mfma(const float* __restrict__ Wt,   // [B,H,L,L] f32
               const bf16* __restrict__ vT,    // [32][64][2048] bf16
               bf16* __restrict__ Vals) {      // [B,L,E] bf16
    const int t = threadIdx.x, l = t & 63, w = t >> 6;
    const int bh = blockIdx.x;
    const int q0 = (31 - (int)blockIdx.y) * 64;      // heavy tiles first
    const int qg = q0 + w * 16 + (l & 15);
    const float* wrow = Wt + (size_t)bh * TL * TL + (size_t)qg * TL;
    const bf16* vTb = vT + (size_t)bh * TA * TL;
    const int kq = (l >> 4) * 8;                     // k sub-offset (elems)

    f32x4 acc[4] = {};
    float rs = 0.f;
    const int nk = (q0 >> 6) + 1;

    #pragma unroll 1
    for (int kt = 0; kt < nk; ++kt) {
        const int k0 = kt << 6;
        bf16x8 bfr[4][2];
        #pragma unroll
        for (int nf = 0; nf < 4; ++nf)
            #pragma unroll
            for (int kk = 0; kk < 2; ++kk)
                bfr[nf][kk] = *reinterpret_cast<const bf16x8*>(
                    vTb + (size_t)(nf * 16 + (l & 15)) * TL + k0 + kk * 32 + kq);
        bf16x8 pa[2];
        #pragma unroll
        for (int kk = 0; kk < 2; ++kk) {
            const float* wp = wrow + k0 + kk * 32 + kq;
            const float4 x0 = *reinterpret_cast<const float4*>(wp);
            const float4 x1 = *reinterpret_cast<const float4*>(wp + 4);
            const float xs[8] = {x0.x, x0.y, x0.z, x0.w, x1.x, x1.y, x1.z, x1.w};
            #pragma unroll
            for (int j = 0; j < 8; ++j) {
                const int kgl = k0 + kk * 32 + kq + j;
                const float p = (kgl <= qg) ? __expf(xs[j]) : 0.f;
                rs += p;
                pa[kk][j] = (bf16)p;
            }
        }
        #pragma unroll
        for (int nf = 0; nf < 4; ++nf) {
            acc[nf] = __builtin_amdgcn_mfma_f32_16x16x32_bf16(pa[0], bfr[nf][0], acc[nf], 0, 0, 0);
            acc[nf] = __builtin_amdgcn_mfma_f32_16x16x32_bf16(pa[1], bfr[nf][1], acc[nf], 0, 0, 0);
        }
    }

    rs += __shfl_xor(rs, 16);
    rs += __shfl_xor(rs, 32);
    float inv[4];
    #pragma unroll
    for (int r = 0; r < 4; ++r)
        inv[r] = 1.f / __shfl(rs, ((l >> 4) << 2) + r);

    const int b = bh >> 4, h = bh & 15;
    #pragma unroll
    for (int nf = 0; nf < 4; ++nf) {
        const int e = h * 64 + nf * 16 + (l & 15);
        #pragma unroll
        for (int r = 0; r < 4; ++r) {
            const int qq = q0 + w * 16 + (l >> 4) * 4 + r;
            Vals[(size_t)(b * TL + qq) * TE + e] = (bf16)(acc[nf][r] * inv[r]);
        }
    }
}

extern "C" void kernel_launch(void* const* d_in, const int* in_sizes, int n_in,
                              void* d_out, int out_size, void* d_ws, size_t ws_size,
                              hipStream_t stream) {
    const float* emb   = (const float*)d_in[0];
    const float* wts   = (const float*)d_in[1];
    const float* V_w   = (const float*)d_in[3];
    const float* out_w = (const float*)d_in[4];
    float* out = (float*)d_out;

    bf16* embB = (bf16*)d_ws;                         // 4M elems
    bf16* VwB  = embB + (size_t)4096 * 1024;          // 1M
    bf16* OwB  = VwB + (size_t)1024 * 1024;           // 1M
    bf16* vT   = OwB + (size_t)1024 * 1024;           // 4M  [32][64][2048]
    bf16* vals = vT  + (size_t)4096 * 1024;           // 4M  [B,L,E]

    cvt_all<<<6144, 256, 0, stream>>>(emb, V_w, out_w, embB, VwB, OwB);

    dim3 gg(1024 / 64, 4096 / 64);                    // 16 x 64 = 1024 blocks
    gemm_bt<1><<<gg, 256, 0, stream>>>(embB, VwB, (void*)vT);

    dim3 ga(32, 32);                                  // (bh, q-tile)
    attn_mfma<<<ga, 256, 0, stream>>>(wts, vT, vals);

    gemm_bt<0><<<gg, 256, 0, stream>>>(vals, OwB, (void*)out);
}